// Round 2
// baseline (50937.173 us; speedup 1.0000x reference)
//
#include <hip/hip_runtime.h>

typedef unsigned int u32;

constexpr int Bc = 32;     // batch
constexpr int Tc = 128;    // encoder seq len
constexpr int Ec = 512;    // embed dim
constexpr int Hc = 1024;   // hidden
constexpr int Vc = 32000;  // vocab
constexpr int Lc = 64;     // max_len (decoder steps)

__device__ __forceinline__ void ldf8(const float* p, float* x) {
    float4 a = *(const float4*)p;
    float4 b = *(const float4*)(p + 4);
    x[0] = a.x; x[1] = a.y; x[2] = a.z; x[3] = a.w;
    x[4] = b.x; x[5] = b.y; x[6] = b.z; x[7] = b.w;
}
__device__ __forceinline__ float sigm(float x) { return 1.0f / (1.0f + expf(-x)); }

// ---------------------------------------------------------------------------
// init: zero h/c state, set tok = BOS(1)
// ---------------------------------------------------------------------------
__global__ void init_k(float* st, int n, int* tok) {
    int i = blockIdx.x * blockDim.x + threadIdx.x;
    for (; i < n; i += gridDim.x * blockDim.x) st[i] = 0.0f;
    if (blockIdx.x == 0 && threadIdx.x < Bc) tok[threadIdx.x] = 1;  // BOS
}

// ---------------------------------------------------------------------------
// Fused LSTM cell:  g = x@Wih^T + h@Whh^T + b ; apply gates; h_out, c in-place.
// XMODE 0: x = fp32 buffer [B][KX]
// XMODE 1: x = emb[src[b*T + tcol]]   (fp32, KX == Ec)
// XMODE 2: x = emb[tok[b]]            (fp32, KX == Ec)
// Grid: 512 blocks (2 hk each), 256 threads = 4 k-quarters x (32 b x 2 hk).
// ---------------------------------------------------------------------------
template<int KX, int XMODE>
__global__ __launch_bounds__(256)
void cell_k(const float* __restrict__ Wih, const float* __restrict__ Whh,
            const float* __restrict__ bias,
            const float* __restrict__ xbuf, const float* __restrict__ emb,
            const int* __restrict__ src, int tcol, const int* __restrict__ tok,
            const float* __restrict__ h_in, float* __restrict__ h_out,
            float* __restrict__ c)
{
    const int tid = threadIdx.x;
    const int q   = tid >> 6;          // k-quarter 0..3
    const int oid = tid & 63;
    const int b   = oid & 31;
    const int hj  = oid >> 5;          // 0..1
    const int hk  = blockIdx.x * 2 + hj;

    const float* w0 = Wih + (size_t)(0 * Hc + hk) * KX;
    const float* w1 = Wih + (size_t)(1 * Hc + hk) * KX;
    const float* w2 = Wih + (size_t)(2 * Hc + hk) * KX;
    const float* w3 = Wih + (size_t)(3 * Hc + hk) * KX;
    const float* u0 = Whh + (size_t)(0 * Hc + hk) * Hc;
    const float* u1 = Whh + (size_t)(1 * Hc + hk) * Hc;
    const float* u2 = Whh + (size_t)(2 * Hc + hk) * Hc;
    const float* u3 = Whh + (size_t)(3 * Hc + hk) * Hc;

    float a0 = 0.f, a1 = 0.f, a2 = 0.f, a3 = 0.f;
    float xv[8], w[8];

    // ---- x contribution ----
    const float* xrow = nullptr;
    if constexpr (XMODE == 0) {
        xrow = xbuf + b * KX;
    } else if constexpr (XMODE == 1) {
        xrow = emb + (size_t)src[b * Tc + tcol] * Ec;
    } else {
        xrow = emb + (size_t)tok[b] * Ec;
    }
    {
        const int kq = KX / 4;
        for (int k = q * kq; k < q * kq + kq; k += 8) {
            ldf8(xrow + k, xv);
            ldf8(w0 + k, w);
            #pragma unroll
            for (int i = 0; i < 8; i++) a0 += w[i] * xv[i];
            ldf8(w1 + k, w);
            #pragma unroll
            for (int i = 0; i < 8; i++) a1 += w[i] * xv[i];
            ldf8(w2 + k, w);
            #pragma unroll
            for (int i = 0; i < 8; i++) a2 += w[i] * xv[i];
            ldf8(w3 + k, w);
            #pragma unroll
            for (int i = 0; i < 8; i++) a3 += w[i] * xv[i];
        }
    }
    // ---- h contribution ----
    {
        const float* hrow = h_in + b * Hc;
        const int kq = Hc / 4;   // 256
        for (int k = q * kq; k < q * kq + kq; k += 8) {
            ldf8(hrow + k, xv);
            ldf8(u0 + k, w);
            #pragma unroll
            for (int i = 0; i < 8; i++) a0 += w[i] * xv[i];
            ldf8(u1 + k, w);
            #pragma unroll
            for (int i = 0; i < 8; i++) a1 += w[i] * xv[i];
            ldf8(u2 + k, w);
            #pragma unroll
            for (int i = 0; i < 8; i++) a2 += w[i] * xv[i];
            ldf8(u3 + k, w);
            #pragma unroll
            for (int i = 0; i < 8; i++) a3 += w[i] * xv[i];
        }
    }

    __shared__ float red[4][64][4];
    red[q][oid][0] = a0; red[q][oid][1] = a1;
    red[q][oid][2] = a2; red[q][oid][3] = a3;
    __syncthreads();
    if (q == 0) {
        #pragma unroll
        for (int qq = 1; qq < 4; qq++) {
            a0 += red[qq][oid][0]; a1 += red[qq][oid][1];
            a2 += red[qq][oid][2]; a3 += red[qq][oid][3];
        }
        a0 += bias[0 * Hc + hk];
        a1 += bias[1 * Hc + hk];
        a2 += bias[2 * Hc + hk];
        a3 += bias[3 * Hc + hk];
        const float ig = sigm(a0), fg = sigm(a1);
        const float gv = tanhf(a2), og = sigm(a3);
        const int idx = b * Hc + hk;
        const float cn = fg * c[idx] + ig * gv;
        c[idx] = cn;
        h_out[idx] = og * tanhf(cn);
    }
}

// ---------------------------------------------------------------------------
// logits = h1 @ out_W^T + out_b ; write fp32 to d_out[b][s][v]; per-block
// argmax partials (np first-occurrence tie rule).
// Grid: 500 blocks x 64 vocab cols, 256 threads = 32 b x 8 vlanes (8 v each).
// ---------------------------------------------------------------------------
__global__ __launch_bounds__(256)
void logits_k(const float* __restrict__ h1, const float* __restrict__ outW,
              const float* __restrict__ outb, float* __restrict__ out, int s,
              float* __restrict__ pmax, int* __restrict__ pidx)
{
    __shared__ float hl[32][68];     // padded: conflict-free reads
    __shared__ float sval[256];
    __shared__ int   sidx[256];
    const int tid = threadIdx.x;
    const int bq  = tid >> 3;        // batch row 0..31
    const int vl  = tid & 7;         // vocab lane 0..7
    const int v0  = blockIdx.x * 64;

    float acc[8];
    #pragma unroll
    for (int j = 0; j < 8; j++) acc[j] = 0.f;

    const float* wbase = outW + (size_t)(v0 + vl * 8) * Hc;

    for (int kc = 0; kc < 16; kc++) {
        #pragma unroll
        for (int i = 0; i < 2; i++) {
            const int idx4 = tid + i * 256;
            const int bb = idx4 >> 4, kq = idx4 & 15;
            *(float4*)&hl[bb][kq * 4] =
                *(const float4*)(h1 + bb * Hc + kc * 64 + kq * 4);
        }
        __syncthreads();
        #pragma unroll
        for (int i8 = 0; i8 < 8; i8++) {
            float h8[8];
            *(float4*)&h8[0] = *(const float4*)&hl[bq][i8 * 8];
            *(float4*)&h8[4] = *(const float4*)&hl[bq][i8 * 8 + 4];
            const float* wk = wbase + kc * 64 + i8 * 8;
            #pragma unroll
            for (int j = 0; j < 8; j++) {
                float w[8]; ldf8(wk + (size_t)j * Hc, w);
                float t = acc[j];
                #pragma unroll
                for (int i = 0; i < 8; i++) t += w[i] * h8[i];
                acc[j] = t;
            }
        }
        __syncthreads();
    }

    float best = -3.4e38f; int bidx = 0;
    alignas(16) float ob[8];
    #pragma unroll
    for (int j = 0; j < 8; j++) {
        const int v = v0 + vl * 8 + j;
        const float val = acc[j] + outb[v];
        ob[j] = val;
        if (val > best) { best = val; bidx = v; }   // ascending v: '>' = first occurrence
    }
    float* dst = out + (size_t)(bq * Lc + s) * Vc + v0 + vl * 8;
    *(float4*)dst       = *(const float4*)&ob[0];
    *(float4*)(dst + 4) = *(const float4*)&ob[4];

    sval[tid] = best; sidx[tid] = bidx;
    __syncthreads();
    if (vl == 0) {
        #pragma unroll
        for (int u = 1; u < 8; u++) {
            const float v2 = sval[tid + u]; const int i2 = sidx[tid + u];
            if (v2 > best || (v2 == best && i2 < bidx)) { best = v2; bidx = i2; }
        }
        pmax[blockIdx.x * 32 + bq] = best;
        pidx[blockIdx.x * 32 + bq] = bidx;
    }
}

// ---------------------------------------------------------------------------
// final argmax over 500 partials per batch row -> tok
// ---------------------------------------------------------------------------
__global__ __launch_bounds__(256)
void argmax_fin_k(const float* __restrict__ pmax, const int* __restrict__ pidx,
                  int* __restrict__ tok)
{
    __shared__ float sv[256];
    __shared__ int   si[256];
    const int b = blockIdx.x, tid = threadIdx.x;
    float best = -3.4e38f; int bidx = 0x7fffffff;
    for (int j = tid; j < 500; j += 256) {
        const float v = pmax[j * 32 + b]; const int i = pidx[j * 32 + b];
        if (v > best || (v == best && i < bidx)) { best = v; bidx = i; }
    }
    sv[tid] = best; si[tid] = bidx;
    __syncthreads();
    for (int st = 128; st > 0; st >>= 1) {
        if (tid < st) {
            const float v = sv[tid + st]; const int i = si[tid + st];
            if (v > sv[tid] || (v == sv[tid] && i < si[tid])) { sv[tid] = v; si[tid] = i; }
        }
        __syncthreads();
    }
    if (tid == 0) tok[b] = si[0];
}

// ---------------------------------------------------------------------------
extern "C" void kernel_launch(void* const* d_in, const int* in_sizes, int n_in,
                              void* d_out, int out_size, void* d_ws, size_t ws_size,
                              hipStream_t stream)
{
    const int*   src = (const int*)d_in[0];
    const float* emb = (const float*)d_in[1];
    const float* eW0 = (const float*)d_in[2];
    const float* eU0 = (const float*)d_in[3];
    const float* eb0 = (const float*)d_in[4];
    const float* eW1 = (const float*)d_in[5];
    const float* eU1 = (const float*)d_in[6];
    const float* eb1 = (const float*)d_in[7];
    const float* dW0 = (const float*)d_in[8];
    const float* dU0 = (const float*)d_in[9];
    const float* db0 = (const float*)d_in[10];
    const float* dW1 = (const float*)d_in[11];
    const float* dU1 = (const float*)d_in[12];
    const float* db1 = (const float*)d_in[13];
    const float* oW  = (const float*)d_in[14];
    const float* obv = (const float*)d_in[15];
    float* out = (float*)d_out;

    float* ws   = (float*)d_ws;
    float* h0   = ws;                   // [2][32][1024]
    float* c0   = ws + 65536;           // [32][1024]
    float* h1   = ws + 98304;           // [2][32][1024]
    float* c1   = ws + 163840;          // [32][1024]
    int*   tok  = (int*)(ws + 196608);  // [32]
    float* pmax = ws + 196672;          // [500][32]
    int*   pidx = (int*)(ws + 212672);  // [500][32]

    init_k<<<128, 256, 0, stream>>>(ws, 196608, tok);

    // ---- encoder: 128 steps, layer0 then layer1 per step ----
    for (int t = 0; t < Tc; t++) {
        const int r = t & 1, w = 1 - r;
        cell_k<Ec, 1><<<512, 256, 0, stream>>>(
            eW0, eU0, eb0, nullptr, emb, src, t, nullptr,
            h0 + r * 32768, h0 + w * 32768, c0);
        cell_k<Hc, 0><<<512, 256, 0, stream>>>(
            eW1, eU1, eb1, h0 + w * 32768, nullptr, nullptr, 0, nullptr,
            h1 + r * 32768, h1 + w * 32768, c1);
    }

    // ---- decoder: 64 greedy steps ----
    for (int s = 0; s < Lc; s++) {
        const int r = s & 1, w = 1 - r;
        cell_k<Ec, 2><<<512, 256, 0, stream>>>(
            dW0, dU0, db0, nullptr, emb, nullptr, 0, tok,
            h0 + r * 32768, h0 + w * 32768, c0);
        cell_k<Hc, 0><<<512, 256, 0, stream>>>(
            dW1, dU1, db1, h0 + w * 32768, nullptr, nullptr, 0, nullptr,
            h1 + r * 32768, h1 + w * 32768, c1);
        logits_k<<<500, 256, 0, stream>>>(
            h1 + w * 32768, oW, obv, out, s, pmax, pidx);
        argmax_fin_k<<<32, 256, 0, stream>>>(pmax, pidx, tok);
    }
    (void)in_sizes; (void)n_in; (void)out_size; (void)ws_size;
}